// Round 2
// 1383.664 us; speedup vs baseline: 1.0058x; 1.0058x over previous
//
#include <hip/hip_runtime.h>

// Problem: x (32,256,256,128) fp32 NHWC, pool=stride=(2,2), per-window softmax
// entropy over the 4 window elements (per channel), then per-channel affine.
// out: (32,128,128,128) fp32.
//
// entropy = log(s) - (sum ei*(xi-m))/s,  ei = exp(xi-m), s = sum ei
//
// Traffic floor: 1.074 GB read + 0.268 GB write = 1.342 GB  (~215 us @ 6.3 TB/s).
// This version: 2 windows (8 float4 loads) per thread, persistent grid-stride
// (2048 blocks, stride % 32 == 0 so w/bias are hoisted out of the loop),
// nontemporal loads/stores on the streaming tensors.

#define B_  32
#define H_  256
#define W_  256
#define C_  128
#define HO_ 128
#define WO_ 128

// Each work-item: 2 adjacent output pixels x 4 channels.
// 32 * 128 * 64 * 32 = 8,388,608 work-items.
#define TOTAL_WI (B_ * HO_ * (WO_ / 2) * (C_ / 4))

typedef float f32x4 __attribute__((ext_vector_type(4)));

__device__ __forceinline__ float entropy1(float a0, float a1, float a2, float a3) {
    const float m  = fmaxf(fmaxf(a0, a1), fmaxf(a2, a3));
    const float d0 = a0 - m, d1 = a1 - m, d2 = a2 - m, d3 = a3 - m;
    const float e0 = __expf(d0), e1 = __expf(d1), e2 = __expf(d2), e3 = __expf(d3);
    const float s  = e0 + e1 + e2 + e3;
    const float ws = e0 * d0 + e1 * d1 + e2 * d2 + e3 * d3;
    return __logf(s) - ws * __frcp_rn(s);
}

__device__ __forceinline__ f32x4 win_entropy(f32x4 v00, f32x4 v01, f32x4 v10, f32x4 v11,
                                             f32x4 wv, f32x4 bv) {
    f32x4 r;
    r.x = entropy1(v00.x, v01.x, v10.x, v11.x) * wv.x + bv.x;
    r.y = entropy1(v00.y, v01.y, v10.y, v11.y) * wv.y + bv.y;
    r.z = entropy1(v00.z, v01.z, v10.z, v11.z) * wv.z + bv.z;
    r.w = entropy1(v00.w, v01.w, v10.w, v11.w) * wv.w + bv.w;
    return r;
}

__global__ __launch_bounds__(256) void entropy_pool_kernel(
    const f32x4* __restrict__ x,     // C/4 = 32 float4 per pixel
    const float* __restrict__ w,
    const float* __restrict__ bias,
    f32x4* __restrict__ out)
{
    const unsigned tid0   = blockIdx.x * blockDim.x + threadIdx.x;
    const unsigned stride = gridDim.x * blockDim.x;   // multiple of 32 -> c4 invariant
    const unsigned c4     = tid0 & 31u;

    // Per-channel affine params: loop-invariant, loaded once (L1-resident broadcast).
    const f32x4 wv = ((const f32x4*)w)[c4];
    const f32x4 bv = ((const f32x4*)bias)[c4];

    for (unsigned t = tid0; t < (unsigned)TOTAL_WI; t += stride) {
        // t layout: c4 (5b) | wo2 (6b) | ho (7b) | b (5b)
        const unsigned wo2 = (t >> 5) & 63u;
        const unsigned ho  = (t >> 11) & 127u;
        const unsigned b   = t >> 18;

        // Input base in float4 units: pixel stride 32, row stride 8192.
        const unsigned base = ((b * H_ + 2u * ho) * W_ + 4u * wo2) * (C_ / 4) + c4;

        // Row 2*ho: pixels 4*wo2 .. 4*wo2+3
        const f32x4 p0 = __builtin_nontemporal_load(&x[base]);
        const f32x4 p1 = __builtin_nontemporal_load(&x[base + 32]);
        const f32x4 p2 = __builtin_nontemporal_load(&x[base + 64]);
        const f32x4 p3 = __builtin_nontemporal_load(&x[base + 96]);
        // Row 2*ho+1
        const f32x4 q0 = __builtin_nontemporal_load(&x[base + 8192]);
        const f32x4 q1 = __builtin_nontemporal_load(&x[base + 8192 + 32]);
        const f32x4 q2 = __builtin_nontemporal_load(&x[base + 8192 + 64]);
        const f32x4 q3 = __builtin_nontemporal_load(&x[base + 8192 + 96]);

        // Window A = pixels (p0,p1 | q0,q1), window B = (p2,p3 | q2,q3)
        const f32x4 rA = win_entropy(p0, p1, q0, q1, wv, bv);
        const f32x4 rB = win_entropy(p2, p3, q2, q3, wv, bv);

        const unsigned obase = ((b * HO_ + ho) * WO_ + 2u * wo2) * (C_ / 4) + c4;
        __builtin_nontemporal_store(rA, &out[obase]);
        __builtin_nontemporal_store(rB, &out[obase + 32]);
    }
}

extern "C" void kernel_launch(void* const* d_in, const int* in_sizes, int n_in,
                              void* d_out, int out_size, void* d_ws, size_t ws_size,
                              hipStream_t stream) {
    const f32x4* x   = (const f32x4*)d_in[0];
    const float* w   = (const float*)d_in[1];
    const float* bia = (const float*)d_in[2];
    f32x4* out       = (f32x4*)d_out;

    // Persistent grid: 2048 blocks x 256 threads = 524288 threads (stride % 32 == 0),
    // 16 grid-stride iterations each.
    const int threads = 256;
    const int blocks  = 2048;
    entropy_pool_kernel<<<blocks, threads, 0, stream>>>(x, w, bia, out);
}